// Round 11
// baseline (63.943 us; speedup 1.0000x reference)
//
#include <hip/hip_runtime.h>
#include <math.h>

#define SD 39
#define BLOCK 256

// ---- packed weight layout in d_ws (float offsets) ----
#define LW1   0      // [64][40]  rows padded to 40 (idx 39 = 0.0f)
#define LB1   2560   // [64]
#define LW2T  2624   // [64][32]  transposed: w2t[o1][o2] = ew2[o2*64+o1]
#define LB2   4672   // [32]
#define LW3   4704   // [4][32]
#define LB3   4832   // [4]
#define LQPE  4836   // [4]  qp[0,2,4,6]
#define LDW1  4840   // [32][4]
#define LDB1  4968   // [32]
#define LDW2  5000   // [16][32]
#define LDB2  5512   // [16]
#define LDW3  5528   // [8][16]
#define LDB3  5656   // [8]
#define WTOT  5664

typedef float vf4 __attribute__((ext_vector_type(4)));
typedef float f2  __attribute__((ext_vector_type(2)));

static __device__ __forceinline__ f2 sp(float x) { f2 r; r.x = x; r.y = x; return r; }
static __device__ __forceinline__ f2 ffma(f2 a, f2 b, f2 c) {
    return __builtin_elementwise_fma(a, b, c);
}

__global__ void repack_kernel(
    const float* __restrict__ ew1, const float* __restrict__ eb1,
    const float* __restrict__ ew2, const float* __restrict__ eb2,
    const float* __restrict__ ew3, const float* __restrict__ eb3,
    const float* __restrict__ qp,
    const float* __restrict__ dw1, const float* __restrict__ db1,
    const float* __restrict__ dw2, const float* __restrict__ db2,
    const float* __restrict__ dw3, const float* __restrict__ db3,
    float* __restrict__ ws)
{
    const int t = threadIdx.x + blockIdx.x * blockDim.x;
    const int stride = blockDim.x * gridDim.x;
    for (int i = t; i < 64 * 40; i += stride) {              // W1 padded to 40
        int o = i / 40, k = i % 40;
        ws[LW1 + i] = (k < SD) ? ew1[o * SD + k] : 0.0f;
    }
    for (int i = t; i < 64; i += stride) ws[LB1 + i] = eb1[i];
    for (int i = t; i < 2048; i += stride) {                 // W2 transposed
        int o1 = i / 32, o2 = i % 32;
        ws[LW2T + i] = ew2[o2 * 64 + o1];
    }
    for (int i = t; i < 32; i += stride)  ws[LB2 + i] = eb2[i];
    for (int i = t; i < 128; i += stride) ws[LW3 + i] = ew3[i];
    for (int i = t; i < 4; i += stride)   ws[LB3 + i] = eb3[i];
    for (int i = t; i < 4; i += stride)   ws[LQPE + i] = qp[2 * i];
    for (int i = t; i < 128; i += stride) ws[LDW1 + i] = dw1[i];
    for (int i = t; i < 32; i += stride)  ws[LDB1 + i] = db1[i];
    for (int i = t; i < 512; i += stride) ws[LDW2 + i] = dw2[i];
    for (int i = t; i < 16; i += stride)  ws[LDB2 + i] = db2[i];
    for (int i = t; i < 128; i += stride) ws[LDW3 + i] = dw3[i];
    for (int i = t; i < 8; i += stride)   ws[LDB3 + i] = db3[i];
}

__global__ __launch_bounds__(BLOCK)
__attribute__((amdgpu_waves_per_eu(2, 2)))   // pin: 2 waves/SIMD, VGPR<=256;
                                             // don't squeeze regs for more.
void qnet_kernel(const float* __restrict__ state,
                 const float* __restrict__ wsf,
                 float* __restrict__ out)
{
    const int tid = threadIdx.x;
    // Two rows per thread, 256 apart: every weight s_load feeds 2 FMAs
    // (stall-per-FLOP halved), two independent chains (ILP x2), and the
    // float2 form lets LLVM emit v_pk_fma_f32 where profitable.
    const size_t r0 = (size_t)blockIdx.x * (2 * BLOCK) + tid;
    const size_t r1 = r0 + BLOCK;

    const float* rp0 = state + r0 * SD;
    const float* rp1 = state + r1 * SD;

    // ---- row loads: opaque asm, 2x10 dwordx4, forced resident in VGPRs ----
    // offsets 0..128 cover floats 0..35; offset 140 covers 35..38 (ends at
    // byte 156 exactly -> no OOB on the final row).
    vf4 a0,a1,a2,a3,a4,a5,a6,a7,a8,a9;
    vf4 c0,c1,c2,c3,c4,c5,c6,c7,c8,c9;
    asm volatile(
        "global_load_dwordx4 %0, %20, off\n\t"
        "global_load_dwordx4 %1, %20, off offset:16\n\t"
        "global_load_dwordx4 %2, %20, off offset:32\n\t"
        "global_load_dwordx4 %3, %20, off offset:48\n\t"
        "global_load_dwordx4 %4, %20, off offset:64\n\t"
        "global_load_dwordx4 %5, %20, off offset:80\n\t"
        "global_load_dwordx4 %6, %20, off offset:96\n\t"
        "global_load_dwordx4 %7, %20, off offset:112\n\t"
        "global_load_dwordx4 %8, %20, off offset:128\n\t"
        "global_load_dwordx4 %9, %20, off offset:140\n\t"
        "global_load_dwordx4 %10, %21, off\n\t"
        "global_load_dwordx4 %11, %21, off offset:16\n\t"
        "global_load_dwordx4 %12, %21, off offset:32\n\t"
        "global_load_dwordx4 %13, %21, off offset:48\n\t"
        "global_load_dwordx4 %14, %21, off offset:64\n\t"
        "global_load_dwordx4 %15, %21, off offset:80\n\t"
        "global_load_dwordx4 %16, %21, off offset:96\n\t"
        "global_load_dwordx4 %17, %21, off offset:112\n\t"
        "global_load_dwordx4 %18, %21, off offset:128\n\t"
        "global_load_dwordx4 %19, %21, off offset:140\n\t"
        "s_waitcnt vmcnt(0)"
        : "=&v"(a0), "=&v"(a1), "=&v"(a2), "=&v"(a3), "=&v"(a4),
          "=&v"(a5), "=&v"(a6), "=&v"(a7), "=&v"(a8), "=&v"(a9),
          "=&v"(c0), "=&v"(c1), "=&v"(c2), "=&v"(c3), "=&v"(c4),
          "=&v"(c5), "=&v"(c6), "=&v"(c7), "=&v"(c8), "=&v"(c9)
        : "v"(rp0), "v"(rp1));

    // pack rows into float2 lanes: xs[i] = {row0[i], row1[i]}
    f2 xs[40];
    #pragma unroll
    for (int j = 0; j < 4; j++) {
        xs[0+j].x=a0[j];  xs[0+j].y=c0[j];   xs[4+j].x=a1[j];  xs[4+j].y=c1[j];
        xs[8+j].x=a2[j];  xs[8+j].y=c2[j];   xs[12+j].x=a3[j]; xs[12+j].y=c3[j];
        xs[16+j].x=a4[j]; xs[16+j].y=c4[j];  xs[20+j].x=a5[j]; xs[20+j].y=c5[j];
        xs[24+j].x=a6[j]; xs[24+j].y=c6[j];  xs[28+j].x=a7[j]; xs[28+j].y=c7[j];
        xs[32+j].x=a8[j]; xs[32+j].y=c8[j];
    }
    xs[36].x=a9[1]; xs[36].y=c9[1];
    xs[37].x=a9[2]; xs[37].y=c9[2];
    xs[38].x=a9[3]; xs[38].y=c9[3];
    xs[39] = sp(0.0f);                       // pairs with the 0.0 pad weight

    // ---- FUSED encoder layers 1+2: 39 -> 64 -> 32 (both rows at once) ----
    f2 acc2[32];
    #pragma unroll
    for (int o = 0; o < 32; o++) acc2[o] = sp(wsf[LB2 + o]);

    #pragma unroll 2
    for (int o1 = 0; o1 < 64; o1++) {
        const float* w1r = wsf + LW1 + o1 * 40;    // uniform -> s_load stream
        f2 a = sp(wsf[LB1 + o1]);
        #pragma unroll
        for (int i = 0; i < 40; i++) a = ffma(xs[i], sp(w1r[i]), a);
        a = __builtin_elementwise_max(a, sp(0.0f));
        const float* w2c = wsf + LW2T + o1 * 32;
        #pragma unroll
        for (int o2 = 0; o2 < 32; o2++)
            acc2[o2] = ffma(a, sp(w2c[o2]), acc2[o2]);
    }
    #pragma unroll
    for (int o = 0; o < 32; o++)                   // in-place ReLU (h2)
        acc2[o] = __builtin_elementwise_max(acc2[o], sp(0.0f));

    // ---- encoder layer 3: 32 -> 4, fast tanh; analytic quantum expvals ----
    // ev_i = prod_{j<=i} cos(enc_j*pi + qp[2j])  (RZ cancels under Z-measure;
    // CNOT chain -> bit i = b0^..^bi; independence factorizes expectation)
    f2 ev[4];
    f2 cprod = sp(1.0f);
    #pragma unroll
    for (int o = 0; o < 4; o++) {
        const float* w = wsf + LW3 + o * 32;
        f2 acc = sp(wsf[LB3 + o]);
        #pragma unroll
        for (int i = 0; i < 32; i++) acc = ffma(acc2[i], sp(w[i]), acc);
        // tanh(x) = 1 - 2/(e^{2x}+1), exact at saturation; then theta, cos
        float qpe = wsf[LQPE + o];
        float ex = __expf(2.0f * acc.x), ey = __expf(2.0f * acc.y);
        float tx = 1.0f - 2.0f / (ex + 1.0f), ty = 1.0f - 2.0f / (ey + 1.0f);
        cprod.x *= __cosf(fmaf(tx, 3.14159265358979323846f, qpe));
        cprod.y *= __cosf(fmaf(ty, 3.14159265358979323846f, qpe));
        ev[o] = cprod;
    }

    // ---- decoder ----
    f2 d1[32];
    #pragma unroll 4
    for (int o = 0; o < 32; o++) {
        const float* w = wsf + LDW1 + o * 4;
        f2 acc = sp(wsf[LDB1 + o]);
        #pragma unroll
        for (int i = 0; i < 4; i++) acc = ffma(ev[i], sp(w[i]), acc);
        d1[o] = __builtin_elementwise_max(acc, sp(0.0f));
    }
    f2 d2[16];
    #pragma unroll 4
    for (int o = 0; o < 16; o++) {
        const float* w = wsf + LDW2 + o * 32;
        f2 acc = sp(wsf[LDB2 + o]);
        #pragma unroll
        for (int i = 0; i < 32; i++) acc = ffma(d1[i], sp(w[i]), acc);
        d2[o] = __builtin_elementwise_max(acc, sp(0.0f));
    }
    f2 o8[8];
    #pragma unroll
    for (int o = 0; o < 8; o++) {
        const float* w = wsf + LDW3 + o * 16;
        f2 acc = sp(wsf[LDB3 + o]);
        #pragma unroll
        for (int i = 0; i < 16; i++) acc = ffma(d2[i], sp(w[i]), acc);
        o8[o] = acc;
    }

    float4* op0 = (float4*)(out + r0 * 8);
    op0[0] = make_float4(o8[0].x, o8[1].x, o8[2].x, o8[3].x);
    op0[1] = make_float4(o8[4].x, o8[5].x, o8[6].x, o8[7].x);
    float4* op1 = (float4*)(out + r1 * 8);
    op1[0] = make_float4(o8[0].y, o8[1].y, o8[2].y, o8[3].y);
    op1[1] = make_float4(o8[4].y, o8[5].y, o8[6].y, o8[7].y);
}

extern "C" void kernel_launch(void* const* d_in, const int* in_sizes, int n_in,
                              void* d_out, int out_size, void* d_ws, size_t ws_size,
                              hipStream_t stream) {
    const float* state = (const float*)d_in[0];
    const float* ew1 = (const float*)d_in[1];
    const float* eb1 = (const float*)d_in[2];
    const float* ew2 = (const float*)d_in[3];
    const float* eb2 = (const float*)d_in[4];
    const float* ew3 = (const float*)d_in[5];
    const float* eb3 = (const float*)d_in[6];
    const float* qp  = (const float*)d_in[7];
    const float* dw1 = (const float*)d_in[8];
    const float* db1 = (const float*)d_in[9];
    const float* dw2 = (const float*)d_in[10];
    const float* db2 = (const float*)d_in[11];
    const float* dw3 = (const float*)d_in[12];
    const float* db3 = (const float*)d_in[13];
    float* out = (float*)d_out;
    float* ws  = (float*)d_ws;

    const int B = in_sizes[0] / SD;

    hipLaunchKernelGGL(repack_kernel, dim3(8), dim3(256), 0, stream,
                       ew1, eb1, ew2, eb2, ew3, eb3, qp,
                       dw1, db1, dw2, db2, dw3, db3, ws);

    const int grid = B / (2 * BLOCK);    // B = 262144 -> 512 blocks, no tail
    hipLaunchKernelGGL(qnet_kernel, dim3(grid), dim3(BLOCK), 0, stream,
                       state, ws, out);
}

// Round 12
// 55.225 us; speedup vs baseline: 1.1579x; 1.1579x over previous
//
#include <hip/hip_runtime.h>
#include <math.h>

#define SD 39
#define BLOCK 256

// ---- repacked weight layout in d_ws (float offsets) ----
#define OFF_W1   0      // [64][48]  (39 used, padded)
#define OFF_B1   3072   // [64]
#define OFF_W2T  3136   // [64][32]  transposed: w2t[o1][o2] = ew2[o2*64+o1]
#define OFF_B2   5184   // [32]
#define OFF_W3   5216   // [4][32]
#define OFF_B3   5344   // [4]
#define OFF_QPE  5360   // [4]  qp[0,2,4,6]
#define OFF_DW1  5376   // [32][4]
#define OFF_DB1  5504   // [32]
#define OFF_DW2  5536   // [16][32]
#define OFF_DB2  6048   // [16]
#define OFF_DW3  6064   // [8][16]
#define OFF_DB3  6192   // [8]
#define WS_FLOATS 6200

typedef float vf4 __attribute__((ext_vector_type(4)));

__global__ void repack_kernel(
    const float* __restrict__ ew1, const float* __restrict__ eb1,
    const float* __restrict__ ew2, const float* __restrict__ eb2,
    const float* __restrict__ ew3, const float* __restrict__ eb3,
    const float* __restrict__ qp,
    const float* __restrict__ dw1, const float* __restrict__ db1,
    const float* __restrict__ dw2, const float* __restrict__ db2,
    const float* __restrict__ dw3, const float* __restrict__ db3,
    float* __restrict__ ws)
{
    const int t = threadIdx.x + blockIdx.x * blockDim.x;
    const int stride = blockDim.x * gridDim.x;
    for (int i = t; i < 64 * 48; i += stride) {              // W1 padded
        int o = i / 48, k = i % 48;
        ws[OFF_W1 + i] = (k < SD) ? ew1[o * SD + k] : 0.0f;
    }
    for (int i = t; i < 64; i += stride) ws[OFF_B1 + i] = eb1[i];
    for (int i = t; i < 2048; i += stride) {                 // W2 transposed
        int o1 = i / 32, o2 = i % 32;
        ws[OFF_W2T + i] = ew2[o2 * 64 + o1];
    }
    for (int i = t; i < 32; i += stride)  ws[OFF_B2 + i] = eb2[i];
    for (int i = t; i < 128; i += stride) ws[OFF_W3 + i] = ew3[i];
    for (int i = t; i < 4; i += stride)   ws[OFF_B3 + i] = eb3[i];
    for (int i = t; i < 4; i += stride)   ws[OFF_QPE + i] = qp[2 * i];
    for (int i = t; i < 128; i += stride) ws[OFF_DW1 + i] = dw1[i];
    for (int i = t; i < 32; i += stride)  ws[OFF_DB1 + i] = db1[i];
    for (int i = t; i < 512; i += stride) ws[OFF_DW2 + i] = dw2[i];
    for (int i = t; i < 16; i += stride)  ws[OFF_DB2 + i] = db2[i];
    for (int i = t; i < 128; i += stride) ws[OFF_DW3 + i] = dw3[i];
    for (int i = t; i < 8; i += stride)   ws[OFF_DB3 + i] = db3[i];
}

__global__ __launch_bounds__(BLOCK)
__attribute__((amdgpu_num_vgpr(128)))   // direct allocation request: bypass the
                                        // occupancy heuristic that pinned us at
                                        // 52 arch-VGPRs and forced AGPR shuttling
void qnet_kernel(const float* __restrict__ state,
                 const float* __restrict__ wsf,
                 float* __restrict__ out)
{
    const int row = blockIdx.x * BLOCK + threadIdx.x;   // B % 256 == 0: no tail

    // ---- row load: opaque asm, 10x dwordx4, forced to stay in VGPRs ----
    // offsets 0..128 cover floats 0..35; offset 140 covers floats 35..38
    // (exactly ends at byte 156 -> no OOB read on the last row).
    const float* rp = state + (size_t)row * SD;
    vf4 g0, g1, g2, g3, g4, g5, g6, g7, g8, g9;
    asm volatile(
        "global_load_dwordx4 %0, %10, off\n\t"
        "global_load_dwordx4 %1, %10, off offset:16\n\t"
        "global_load_dwordx4 %2, %10, off offset:32\n\t"
        "global_load_dwordx4 %3, %10, off offset:48\n\t"
        "global_load_dwordx4 %4, %10, off offset:64\n\t"
        "global_load_dwordx4 %5, %10, off offset:80\n\t"
        "global_load_dwordx4 %6, %10, off offset:96\n\t"
        "global_load_dwordx4 %7, %10, off offset:112\n\t"
        "global_load_dwordx4 %8, %10, off offset:128\n\t"
        "global_load_dwordx4 %9, %10, off offset:140\n\t"
        "s_waitcnt vmcnt(0)"
        : "=&v"(g0), "=&v"(g1), "=&v"(g2), "=&v"(g3), "=&v"(g4),
          "=&v"(g5), "=&v"(g6), "=&v"(g7), "=&v"(g8), "=&v"(g9)
        : "v"(rp));

    float s[SD];
    #pragma unroll
    for (int j = 0; j < 4; j++) { s[0+j]=g0[j]; s[4+j]=g1[j]; s[8+j]=g2[j];
        s[12+j]=g3[j]; s[16+j]=g4[j]; s[20+j]=g5[j]; s[24+j]=g6[j];
        s[28+j]=g7[j]; s[32+j]=g8[j]; }
    s[36] = g9[1]; s[37] = g9[2]; s[38] = g9[3];

    // ---- FUSED encoder layers 1+2: 39 -> 64 -> 32 ----
    // Weights stream as contiguous wide s_loads from the repacked buffer;
    // w2 is pre-transposed so the o2 inner loop is contiguous.
    float acc2[32];
    #pragma unroll
    for (int o = 0; o < 32; o++) acc2[o] = wsf[OFF_B2 + o];

    #pragma unroll 2
    for (int o1 = 0; o1 < 64; o1++) {
        const float* w1r = wsf + OFF_W1 + o1 * 48;
        float a = wsf[OFF_B1 + o1];
        #pragma unroll
        for (int i = 0; i < SD; i++) a = fmaf(s[i], w1r[i], a);
        a = fmaxf(a, 0.0f);
        const float* w2c = wsf + OFF_W2T + o1 * 32;
        #pragma unroll
        for (int o2 = 0; o2 < 32; o2++)
            acc2[o2] = fmaf(a, w2c[o2], acc2[o2]);
    }

    float h2[32];
    #pragma unroll
    for (int o = 0; o < 32; o++) h2[o] = fmaxf(acc2[o], 0.0f);

    // ---- encoder layer 3: 32 -> 4, fast tanh; analytic quantum expvals ----
    // ev_i = prod_{j<=i} cos(enc_j*pi + qp[2j])  (RZ cancels under Z-measure;
    // CNOT chain -> bit i = b0^..^bi; independence factorizes expectation)
    float ev[4];
    float cprod = 1.0f;
    #pragma unroll
    for (int o = 0; o < 4; o++) {
        const float* w = wsf + OFF_W3 + o * 32;
        float acc = wsf[OFF_B3 + o];
        #pragma unroll
        for (int i = 0; i < 32; i++) acc = fmaf(h2[i], w[i], acc);
        float e = __expf(2.0f * acc);                 // tanh = 1 - 2/(e^{2x}+1)
        float enc = 1.0f - 2.0f / (e + 1.0f);
        float theta = fmaf(enc, 3.14159265358979323846f, wsf[OFF_QPE + o]);
        cprod *= __cosf(theta);
        ev[o] = cprod;
    }

    // ---- decoder ----
    float d1[32];
    #pragma unroll 4
    for (int o = 0; o < 32; o++) {
        const float* w = wsf + OFF_DW1 + o * 4;
        float acc = wsf[OFF_DB1 + o];
        #pragma unroll
        for (int i = 0; i < 4; i++) acc = fmaf(ev[i], w[i], acc);
        d1[o] = fmaxf(acc, 0.0f);
    }
    float d2[16];
    #pragma unroll 4
    for (int o = 0; o < 16; o++) {
        const float* w = wsf + OFF_DW2 + o * 32;
        float acc = wsf[OFF_DB2 + o];
        #pragma unroll
        for (int i = 0; i < 32; i++) acc = fmaf(d1[i], w[i], acc);
        d2[o] = fmaxf(acc, 0.0f);
    }
    float o8[8];
    #pragma unroll
    for (int o = 0; o < 8; o++) {
        const float* w = wsf + OFF_DW3 + o * 16;
        float acc = wsf[OFF_DB3 + o];
        #pragma unroll
        for (int i = 0; i < 16; i++) acc = fmaf(d2[i], w[i], acc);
        o8[o] = acc;
    }

    float4* op = (float4*)(out + (size_t)row * 8);
    op[0] = make_float4(o8[0], o8[1], o8[2], o8[3]);
    op[1] = make_float4(o8[4], o8[5], o8[6], o8[7]);
}

extern "C" void kernel_launch(void* const* d_in, const int* in_sizes, int n_in,
                              void* d_out, int out_size, void* d_ws, size_t ws_size,
                              hipStream_t stream) {
    const float* state = (const float*)d_in[0];
    const float* ew1 = (const float*)d_in[1];
    const float* eb1 = (const float*)d_in[2];
    const float* ew2 = (const float*)d_in[3];
    const float* eb2 = (const float*)d_in[4];
    const float* ew3 = (const float*)d_in[5];
    const float* eb3 = (const float*)d_in[6];
    const float* qp  = (const float*)d_in[7];
    const float* dw1 = (const float*)d_in[8];
    const float* db1 = (const float*)d_in[9];
    const float* dw2 = (const float*)d_in[10];
    const float* db2 = (const float*)d_in[11];
    const float* dw3 = (const float*)d_in[12];
    const float* db3 = (const float*)d_in[13];
    float* out = (float*)d_out;
    float* ws  = (float*)d_ws;

    const int B = in_sizes[0] / SD;

    hipLaunchKernelGGL(repack_kernel, dim3(8), dim3(256), 0, stream,
                       ew1, eb1, ew2, eb2, ew3, eb3, qp,
                       dw1, db1, dw2, db2, dw3, db3, ws);

    const int grid = (B + BLOCK - 1) / BLOCK;
    hipLaunchKernelGGL(qnet_kernel, dim3(grid), dim3(BLOCK), 0, stream,
                       state, ws, out);
}

// Round 13
// 45.895 us; speedup vs baseline: 1.3933x; 1.2033x over previous
//
#include <hip/hip_runtime.h>
#include <math.h>

#define SD 39
#define BLOCK 256

// ---- packed weight layout in d_ws ----
// fp16 region (half-index):
//   HW1  @ half    0 : [64][40] fp16, K-pairs (k=39 pad = 0)
//   HW2T @ half 2688 : [32 o1-pairs][32 o2] half2 {w2t[2p][o2], w2t[2p+1][o2]}
// fp32 region (float-index):
#define FB1  1280   // [64]   bias1 (bytes 5120..5376)
#define FB2  2368   // [32]   (bytes 9472..)
#define FW3  2400   // [4][32]
#define FB3  2528   // [4]
#define FQPE 2532   // [4] qp[0,2,4,6]
#define FDW1 2536   // [32][4]
#define FDB1 2664   // [32]
#define FDW2 2696   // [16][32]
#define FDB2 3208   // [16]
#define FDW3 3224   // [8][16]
#define FDB3 3352   // [8]  -> total 3360 floats = 13440 B

typedef float vf4 __attribute__((ext_vector_type(4)));
typedef _Float16 h2v __attribute__((ext_vector_type(2)));

__global__ void repack_kernel(
    const float* __restrict__ ew1, const float* __restrict__ eb1,
    const float* __restrict__ ew2, const float* __restrict__ eb2,
    const float* __restrict__ ew3, const float* __restrict__ eb3,
    const float* __restrict__ qp,
    const float* __restrict__ dw1, const float* __restrict__ db1,
    const float* __restrict__ dw2, const float* __restrict__ db2,
    const float* __restrict__ dw3, const float* __restrict__ db3,
    float* __restrict__ ws)
{
    _Float16* wh = (_Float16*)ws;
    const int t = threadIdx.x + blockIdx.x * blockDim.x;
    const int stride = blockDim.x * gridDim.x;
    // W1: [64][40] fp16, pad k=39 with 0
    for (int i = t; i < 64 * 40; i += stride) {
        int o = i / 40, k = i % 40;
        wh[i] = (k < SD) ? (_Float16)ew1[o * SD + k] : (_Float16)0.0f;
    }
    // W2T pairs: half index 2688 + p1*64 + o2*2 + h  = ew2[o2*64 + 2*p1 + h]
    for (int j = t; j < 2048; j += stride) {
        int p1 = j >> 6, rem = j & 63, o2 = rem >> 1, h = rem & 1;
        wh[2688 + j] = (_Float16)ew2[o2 * 64 + 2 * p1 + h];
    }
    for (int i = t; i < 64; i += stride)  ws[FB1 + i] = eb1[i];
    for (int i = t; i < 32; i += stride)  ws[FB2 + i] = eb2[i];
    for (int i = t; i < 128; i += stride) ws[FW3 + i] = ew3[i];
    for (int i = t; i < 4; i += stride)   ws[FB3 + i] = eb3[i];
    for (int i = t; i < 4; i += stride)   ws[FQPE + i] = qp[2 * i];
    for (int i = t; i < 128; i += stride) ws[FDW1 + i] = dw1[i];
    for (int i = t; i < 32; i += stride)  ws[FDB1 + i] = db1[i];
    for (int i = t; i < 512; i += stride) ws[FDW2 + i] = dw2[i];
    for (int i = t; i < 16; i += stride)  ws[FDB2 + i] = db2[i];
    for (int i = t; i < 128; i += stride) ws[FDW3 + i] = dw3[i];
    for (int i = t; i < 8; i += stride)   ws[FDB3 + i] = db3[i];
}

__global__ __launch_bounds__(BLOCK)
void qnet_kernel(const float* __restrict__ state,
                 const float* __restrict__ wf,
                 float* __restrict__ out)
{
    const _Float16* wh = (const _Float16*)wf;
    const h2v* hw1 = (const h2v*)wf;              // [64][20]
    const h2v* hw2 = (const h2v*)(wh + 2688);     // [32][32]

    const int row = blockIdx.x * BLOCK + threadIdx.x;   // B % 256 == 0

    // ---- row load: opaque asm, 10x dwordx4 (proven non-rematerializable) ----
    const float* rp = state + (size_t)row * SD;
    vf4 g0, g1, g2, g3, g4, g5, g6, g7, g8, g9;
    asm volatile(
        "global_load_dwordx4 %0, %10, off\n\t"
        "global_load_dwordx4 %1, %10, off offset:16\n\t"
        "global_load_dwordx4 %2, %10, off offset:32\n\t"
        "global_load_dwordx4 %3, %10, off offset:48\n\t"
        "global_load_dwordx4 %4, %10, off offset:64\n\t"
        "global_load_dwordx4 %5, %10, off offset:80\n\t"
        "global_load_dwordx4 %6, %10, off offset:96\n\t"
        "global_load_dwordx4 %7, %10, off offset:112\n\t"
        "global_load_dwordx4 %8, %10, off offset:128\n\t"
        "global_load_dwordx4 %9, %10, off offset:140\n\t"
        "s_waitcnt vmcnt(0)"
        : "=&v"(g0), "=&v"(g1), "=&v"(g2), "=&v"(g3), "=&v"(g4),
          "=&v"(g5), "=&v"(g6), "=&v"(g7), "=&v"(g8), "=&v"(g9)
        : "v"(rp));

    float s[40];
    #pragma unroll
    for (int j = 0; j < 4; j++) { s[0+j]=g0[j]; s[4+j]=g1[j]; s[8+j]=g2[j];
        s[12+j]=g3[j]; s[16+j]=g4[j]; s[20+j]=g5[j]; s[24+j]=g6[j];
        s[28+j]=g7[j]; s[32+j]=g8[j]; }
    s[36] = g9[1]; s[37] = g9[2]; s[38] = g9[3];
    s[39] = 0.0f;

    // fp16-pack the row: 20 half2 (pairs along K)
    h2v sh[20];
    #pragma unroll
    for (int p = 0; p < 20; p++) {
        h2v v; v[0] = (_Float16)s[2*p]; v[1] = (_Float16)s[2*p+1];
        sh[p] = v;
    }

    // ---- FUSED encoder L1+L2 via v_dot2_f32_f16 (2 MACs/instr, fp32 acc) ----
    float acc2[32];
    #pragma unroll
    for (int o = 0; o < 32; o++) acc2[o] = wf[FB2 + o];

    #pragma unroll 2
    for (int p1 = 0; p1 < 32; p1++) {            // o1 pair = (2p1, 2p1+1)
        const h2v* w1a = hw1 + (2*p1) * 20;      // uniform -> s_load stream
        const h2v* w1b = hw1 + (2*p1+1) * 20;
        float a0 = wf[FB1 + 2*p1];
        float a1 = wf[FB1 + 2*p1 + 1];
        #pragma unroll
        for (int i = 0; i < 20; i++)
            a0 = __builtin_amdgcn_fdot2(sh[i], w1a[i], a0, false);
        #pragma unroll
        for (int i = 0; i < 20; i++)
            a1 = __builtin_amdgcn_fdot2(sh[i], w1b[i], a1, false);
        a0 = fmaxf(a0, 0.0f);
        a1 = fmaxf(a1, 0.0f);
        h2v hp; hp[0] = (_Float16)a0; hp[1] = (_Float16)a1;
        const h2v* w2p = hw2 + p1 * 32;
        #pragma unroll
        for (int o2 = 0; o2 < 32; o2++)
            acc2[o2] = __builtin_amdgcn_fdot2(hp, w2p[o2], acc2[o2], false);
    }

    float h2[32];
    #pragma unroll
    for (int o = 0; o < 32; o++) h2[o] = fmaxf(acc2[o], 0.0f);

    // ---- encoder L3 (fp32): 32 -> 4, fast tanh; analytic quantum expvals ----
    // ev_i = prod_{j<=i} cos(enc_j*pi + qp[2j])  (RZ cancels under Z-measure;
    // CNOT chain -> bit i = b0^..^bi; independence factorizes expectation)
    float ev[4];
    float cprod = 1.0f;
    #pragma unroll
    for (int o = 0; o < 4; o++) {
        const float* w = wf + FW3 + o * 32;
        float acc = wf[FB3 + o];
        #pragma unroll
        for (int i = 0; i < 32; i++) acc = fmaf(h2[i], w[i], acc);
        float e = __expf(2.0f * acc);                 // tanh = 1 - 2/(e^{2x}+1)
        float enc = 1.0f - 2.0f / (e + 1.0f);
        float theta = fmaf(enc, 3.14159265358979323846f, wf[FQPE + o]);
        cprod *= __cosf(theta);
        ev[o] = cprod;
    }

    // ---- decoder (fp32) ----
    float d1[32];
    #pragma unroll 4
    for (int o = 0; o < 32; o++) {
        const float* w = wf + FDW1 + o * 4;
        float acc = wf[FDB1 + o];
        #pragma unroll
        for (int i = 0; i < 4; i++) acc = fmaf(ev[i], w[i], acc);
        d1[o] = fmaxf(acc, 0.0f);
    }
    float d2[16];
    #pragma unroll 4
    for (int o = 0; o < 16; o++) {
        const float* w = wf + FDW2 + o * 32;
        float acc = wf[FDB2 + o];
        #pragma unroll
        for (int i = 0; i < 32; i++) acc = fmaf(d1[i], w[i], acc);
        d2[o] = fmaxf(acc, 0.0f);
    }
    float o8[8];
    #pragma unroll
    for (int o = 0; o < 8; o++) {
        const float* w = wf + FDW3 + o * 16;
        float acc = wf[FDB3 + o];
        #pragma unroll
        for (int i = 0; i < 16; i++) acc = fmaf(d2[i], w[i], acc);
        o8[o] = acc;
    }

    float4* op = (float4*)(out + (size_t)row * 8);
    op[0] = make_float4(o8[0], o8[1], o8[2], o8[3]);
    op[1] = make_float4(o8[4], o8[5], o8[6], o8[7]);
}

extern "C" void kernel_launch(void* const* d_in, const int* in_sizes, int n_in,
                              void* d_out, int out_size, void* d_ws, size_t ws_size,
                              hipStream_t stream) {
    const float* state = (const float*)d_in[0];
    const float* ew1 = (const float*)d_in[1];
    const float* eb1 = (const float*)d_in[2];
    const float* ew2 = (const float*)d_in[3];
    const float* eb2 = (const float*)d_in[4];
    const float* ew3 = (const float*)d_in[5];
    const float* eb3 = (const float*)d_in[6];
    const float* qp  = (const float*)d_in[7];
    const float* dw1 = (const float*)d_in[8];
    const float* db1 = (const float*)d_in[9];
    const float* dw2 = (const float*)d_in[10];
    const float* db2 = (const float*)d_in[11];
    const float* dw3 = (const float*)d_in[12];
    const float* db3 = (const float*)d_in[13];
    float* out = (float*)d_out;
    float* ws  = (float*)d_ws;

    const int B = in_sizes[0] / SD;

    hipLaunchKernelGGL(repack_kernel, dim3(8), dim3(256), 0, stream,
                       ew1, eb1, ew2, eb2, ew3, eb3, qp,
                       dw1, db1, dw2, db2, dw3, db3, ws);

    const int grid = (B + BLOCK - 1) / BLOCK;
    hipLaunchKernelGGL(qnet_kernel, dim3(grid), dim3(BLOCK), 0, stream,
                       state, ws, out);
}

// Round 14
// 28.677 us; speedup vs baseline: 2.2297x; 1.6004x over previous
//
#include <hip/hip_runtime.h>
#include <math.h>

#define SD 39
#define BLOCK 256

typedef _Float16 half8 __attribute__((ext_vector_type(8)));
typedef float f32x4 __attribute__((ext_vector_type(4)));

// ---- d_ws layout (dword offsets). All weight data is pre-packed on device
// into per-lane MFMA fragments: frag arrays are [nfrag][64 lanes] of half8
// (16B) or f32x4 (16B). Slot k-assignments are chosen by US and baked into
// BOTH the weight fragments (here) and the data fragments (main kernel);
// MFMA pairs A-slot(g,j) with B-slot(g,j), so any consistent choice works.
#define DW_AW1 0      // 8 frags  (mt0..3 x ks0..1)   k = ks*32 + 8g + j ; 0 if k>=39
#define DW_AB1 2048   // 4 frags  f32x4 bias: eb1[mt*16+4g+r]
#define DW_AW2 3072   // 4 frags  (mt0..1 x ks0..1)   o1 = ks*32+16*(j>>2)+4g+(j&3)
#define DW_AB2 4096   // 2 frags  eb2[mt*16+4g+r]
#define DW_AW3 4608   // 1 frag   m=c<4: ew3[c][o2], o2=16*(j>>2)+4g+(j&3); else 0
#define DW_AB3 4864   // 1 frag   g==0 ? eb3[r] : 0
#define DW_AD1 5120   // 2 frags  (g==0&&j<4) ? dw1[(mt*16+c)*4+j] : 0
#define DW_AE1 5632   // 2 frags  db1[mt*16+4g+r]
#define DW_AD2 6144   // 1 frag   dw2[c*32 + 16*(j>>2)+4g+(j&3)]
#define DW_AE2 6400   // 1 frag   db2[4g+r]
#define DW_AD3 6656   // 1 frag   (c<8&&j<4) ? dw3[c*16+4g+j] : 0
#define DW_AE3 6912   // 1 frag   (4g+r<8) ? db3[4g+r] : 0
#define DW_QPE 7168   // qp[0,2,4,6]

__global__ void repack_kernel(
    const float* __restrict__ ew1, const float* __restrict__ eb1,
    const float* __restrict__ ew2, const float* __restrict__ eb2,
    const float* __restrict__ ew3, const float* __restrict__ eb3,
    const float* __restrict__ qp,
    const float* __restrict__ dw1, const float* __restrict__ db1,
    const float* __restrict__ dw2, const float* __restrict__ db2,
    const float* __restrict__ dw3, const float* __restrict__ db3,
    float* __restrict__ ws)
{
    _Float16* wh = (_Float16*)ws;
    const int t0 = threadIdx.x + blockIdx.x * blockDim.x;
    const int stride = blockDim.x * gridDim.x;

    // AW1: 8 frags x 512 halves
    for (int i = t0; i < 8 * 512; i += stride) {
        int frag = i >> 9, lane = (i >> 3) & 63, j = i & 7;
        int mt = frag >> 1, ks = frag & 1, g = lane >> 4, c = lane & 15;
        int m = mt * 16 + c, k = ks * 32 + 8 * g + j;
        wh[DW_AW1 * 2 + i] = (k < SD) ? (_Float16)ew1[m * SD + k] : (_Float16)0.0f;
    }
    // AW2: 4 frags
    for (int i = t0; i < 4 * 512; i += stride) {
        int frag = i >> 9, lane = (i >> 3) & 63, j = i & 7;
        int mt = frag >> 1, ks = frag & 1, g = lane >> 4, c = lane & 15;
        int m = mt * 16 + c, o1 = ks * 32 + 16 * (j >> 2) + 4 * g + (j & 3);
        wh[DW_AW2 * 2 + i] = (_Float16)ew2[m * 64 + o1];
    }
    // AW3: 1 frag
    for (int i = t0; i < 512; i += stride) {
        int lane = (i >> 3) & 63, j = i & 7, g = lane >> 4, c = lane & 15;
        int o2 = 16 * (j >> 2) + 4 * g + (j & 3);
        wh[DW_AW3 * 2 + i] = (c < 4) ? (_Float16)ew3[c * 32 + o2] : (_Float16)0.0f;
    }
    // AD1: 2 frags
    for (int i = t0; i < 2 * 512; i += stride) {
        int frag = i >> 9, lane = (i >> 3) & 63, j = i & 7;
        int g = lane >> 4, c = lane & 15, m = frag * 16 + c;
        wh[DW_AD1 * 2 + i] = (g == 0 && j < 4) ? (_Float16)dw1[m * 4 + j] : (_Float16)0.0f;
    }
    // AD2: 1 frag
    for (int i = t0; i < 512; i += stride) {
        int lane = (i >> 3) & 63, j = i & 7, g = lane >> 4, c = lane & 15;
        int k1 = 16 * (j >> 2) + 4 * g + (j & 3);
        wh[DW_AD2 * 2 + i] = (_Float16)dw2[c * 32 + k1];
    }
    // AD3: 1 frag
    for (int i = t0; i < 512; i += stride) {
        int lane = (i >> 3) & 63, j = i & 7, g = lane >> 4, c = lane & 15;
        wh[DW_AD3 * 2 + i] = (c < 8 && j < 4) ? (_Float16)dw3[c * 16 + 4 * g + j]
                                              : (_Float16)0.0f;
    }
    // biases (f32x4 per lane; value depends on output row = 4g+r)
    for (int i = t0; i < 1024; i += stride) {          // AB1: 4 frags
        int mt = i >> 8, lane = (i >> 2) & 63, r = i & 3, g = lane >> 4;
        ws[DW_AB1 + i] = eb1[mt * 16 + 4 * g + r];
    }
    for (int i = t0; i < 512; i += stride) {           // AB2: 2 frags
        int mt = i >> 8, lane = (i >> 2) & 63, r = i & 3, g = lane >> 4;
        ws[DW_AB2 + i] = eb2[mt * 16 + 4 * g + r];
    }
    for (int i = t0; i < 256; i += stride) {           // AB3
        int lane = (i >> 2) & 63, r = i & 3, g = lane >> 4;
        ws[DW_AB3 + i] = (g == 0) ? eb3[r] : 0.0f;
    }
    for (int i = t0; i < 512; i += stride) {           // AE1: 2 frags
        int mt = i >> 8, lane = (i >> 2) & 63, r = i & 3, g = lane >> 4;
        ws[DW_AE1 + i] = db1[mt * 16 + 4 * g + r];
    }
    for (int i = t0; i < 256; i += stride) {           // AE2
        int lane = (i >> 2) & 63, r = i & 3, g = lane >> 4;
        ws[DW_AE2 + i] = db2[4 * g + r];
    }
    for (int i = t0; i < 256; i += stride) {           // AE3
        int lane = (i >> 2) & 63, r = i & 3, g = lane >> 4;
        ws[DW_AE3 + i] = (4 * g + r < 8) ? db3[4 * g + r] : 0.0f;
    }
    for (int i = t0; i < 4; i += stride) ws[DW_QPE + i] = qp[2 * i];
}

__global__ __launch_bounds__(BLOCK)
void qnet_kernel(const float* __restrict__ state,
                 const float* __restrict__ wsf,
                 float* __restrict__ out,
                 int ntiles, int nwaves)
{
    const int lane = threadIdx.x & 63;
    const int g = lane >> 4, c = lane & 15;
    const int gwave = blockIdx.x * (BLOCK / 64) + (threadIdx.x >> 6);

    const half8* hws = (const half8*)wsf;
    const f32x4* fws = (const f32x4*)wsf;
    const float* qpep = wsf + DW_QPE;        // uniform -> s_load

    for (int tile = gwave; tile < ntiles; tile += nwaves) {
        const long long R = (long long)tile * 16;
        const float* sp = state + (R + c) * SD;

        // ---- state B-fragments (n=batch=c; k-slot (g,j): ks0 -> col 8g+j,
        //      ks1 -> col 32+8g+j (weights zero where col>=39)) ----
        float4 s0 = *(const float4*)(sp + 8 * g);
        float4 s1 = *(const float4*)(sp + 8 * g + 4);
        float4 s2 = *(const float4*)(sp + 32);       // cols 32..35
        float4 s3 = *(const float4*)(sp + 35);       // cols 35..38 (in-bounds)
        half8 x0, x1;
        x0[0] = (_Float16)s0.x; x0[1] = (_Float16)s0.y;
        x0[2] = (_Float16)s0.z; x0[3] = (_Float16)s0.w;
        x0[4] = (_Float16)s1.x; x0[5] = (_Float16)s1.y;
        x0[6] = (_Float16)s1.z; x0[7] = (_Float16)s1.w;
        x1[0] = (_Float16)s2.x; x1[1] = (_Float16)s2.y;
        x1[2] = (_Float16)s2.z; x1[3] = (_Float16)s2.w;
        x1[4] = (_Float16)s3.y; x1[5] = (_Float16)s3.z;
        x1[6] = (_Float16)s3.w; x1[7] = (_Float16)0.0f;

        // ---- L1: C1^T[o1][batch], 4 M-tiles x 2 K-steps ----
        f32x4 c1[4];
        #pragma unroll
        for (int mt = 0; mt < 4; mt++) {
            f32x4 acc = fws[DW_AB1 / 4 + mt * 64 + lane];
            acc = __builtin_amdgcn_mfma_f32_16x16x32_f16(
                      hws[DW_AW1 / 4 + (mt * 2 + 0) * 64 + lane], x0, acc, 0, 0, 0);
            acc = __builtin_amdgcn_mfma_f32_16x16x32_f16(
                      hws[DW_AW1 / 4 + (mt * 2 + 1) * 64 + lane], x1, acc, 0, 0, 0);
            c1[mt] = acc;
        }
        // relu + pack into L2 B-frags (slot (g,j) -> o1 = ks*32+16*(j>>2)+4g+(j&3))
        half8 hb0, hb1;
        #pragma unroll
        for (int j = 0; j < 8; j++) {
            hb0[j] = (_Float16)fmaxf(c1[j >> 2][j & 3], 0.0f);
            hb1[j] = (_Float16)fmaxf(c1[2 + (j >> 2)][j & 3], 0.0f);
        }

        // ---- L2: C2^T[o2][batch], 2 M-tiles x 2 K-steps ----
        f32x4 c2[2];
        #pragma unroll
        for (int mt = 0; mt < 2; mt++) {
            f32x4 acc = fws[DW_AB2 / 4 + mt * 64 + lane];
            acc = __builtin_amdgcn_mfma_f32_16x16x32_f16(
                      hws[DW_AW2 / 4 + (mt * 2 + 0) * 64 + lane], hb0, acc, 0, 0, 0);
            acc = __builtin_amdgcn_mfma_f32_16x16x32_f16(
                      hws[DW_AW2 / 4 + (mt * 2 + 1) * 64 + lane], hb1, acc, 0, 0, 0);
            c2[mt] = acc;
        }
        half8 hb2;
        #pragma unroll
        for (int j = 0; j < 8; j++)
            hb2[j] = (_Float16)fmaxf(c2[j >> 2][j & 3], 0.0f);

        // ---- L3: enc^T[e][batch] (rows valid only for g==0; others exact 0) ----
        f32x4 e = __builtin_amdgcn_mfma_f32_16x16x32_f16(
                      hws[DW_AW3 / 4 + lane], hb2, fws[DW_AB3 / 4 + lane], 0, 0, 0);

        // ---- quantum: ev_i = prod_{j<=i} cos(tanh(e_j)*pi + qp[2j]) ----
        // (RZ cancels under Z-measure; CNOT chain -> bit i = b0^..^bi)
        float ev[4]; float cp = 1.0f;
        #pragma unroll
        for (int r = 0; r < 4; r++) {
            float ex = __expf(2.0f * e[r]);              // tanh = 1 - 2/(e^2x+1)
            float enc = 1.0f - 2.0f / (ex + 1.0f);
            float th = fmaf(enc, 3.14159265358979323846f, qpep[r]);
            cp *= __cosf(th);
            ev[r] = cp;
        }
        // ev B-frag: only slots (g==0, j<4) are logically live (AD1 zeros rest);
        // garbage-but-finite values in other lanes are killed by zero weights.
        half8 evb;
        evb[0] = (_Float16)ev[0]; evb[1] = (_Float16)ev[1];
        evb[2] = (_Float16)ev[2]; evb[3] = (_Float16)ev[3];
        evb[4] = (_Float16)0.0f;  evb[5] = (_Float16)0.0f;
        evb[6] = (_Float16)0.0f;  evb[7] = (_Float16)0.0f;

        // ---- D1: 2 M-tiles, K=4(pad32) ----
        f32x4 d1c[2];
        #pragma unroll
        for (int mt = 0; mt < 2; mt++)
            d1c[mt] = __builtin_amdgcn_mfma_f32_16x16x32_f16(
                          hws[DW_AD1 / 4 + mt * 64 + lane], evb,
                          fws[DW_AE1 / 4 + mt * 64 + lane], 0, 0, 0);
        half8 db;
        #pragma unroll
        for (int j = 0; j < 8; j++)
            db[j] = (_Float16)fmaxf(d1c[j >> 2][j & 3], 0.0f);

        // ---- D2: K=32 ----
        f32x4 d2c = __builtin_amdgcn_mfma_f32_16x16x32_f16(
                        hws[DW_AD2 / 4 + lane], db, fws[DW_AE2 / 4 + lane], 0, 0, 0);
        half8 d2b;
        d2b[0] = (_Float16)fmaxf(d2c[0], 0.0f);
        d2b[1] = (_Float16)fmaxf(d2c[1], 0.0f);
        d2b[2] = (_Float16)fmaxf(d2c[2], 0.0f);
        d2b[3] = (_Float16)fmaxf(d2c[3], 0.0f);
        d2b[4] = (_Float16)0.0f; d2b[5] = (_Float16)0.0f;
        d2b[6] = (_Float16)0.0f; d2b[7] = (_Float16)0.0f;

        // ---- D3: K=16(pad32); out rows 0..7 live in g=0 (dims 0-3), g=1 (4-7) ----
        f32x4 o = __builtin_amdgcn_mfma_f32_16x16x32_f16(
                      hws[DW_AD3 / 4 + lane], d2b, fws[DW_AE3 / 4 + lane], 0, 0, 0);

        if (lane < 32) {
            float4* op = (float4*)(out + (R + c) * 8 + 4 * g);
            *op = make_float4(o[0], o[1], o[2], o[3]);
        }
    }
}

extern "C" void kernel_launch(void* const* d_in, const int* in_sizes, int n_in,
                              void* d_out, int out_size, void* d_ws, size_t ws_size,
                              hipStream_t stream) {
    const float* state = (const float*)d_in[0];
    const float* ew1 = (const float*)d_in[1];
    const float* eb1 = (const float*)d_in[2];
    const float* ew2 = (const float*)d_in[3];
    const float* eb2 = (const float*)d_in[4];
    const float* ew3 = (const float*)d_in[5];
    const float* eb3 = (const float*)d_in[6];
    const float* qp  = (const float*)d_in[7];
    const float* dw1 = (const float*)d_in[8];
    const float* db1 = (const float*)d_in[9];
    const float* dw2 = (const float*)d_in[10];
    const float* db2 = (const float*)d_in[11];
    const float* dw3 = (const float*)d_in[12];
    const float* db3 = (const float*)d_in[13];
    float* out = (float*)d_out;
    float* ws  = (float*)d_ws;

    const int B = in_sizes[0] / SD;
    const int ntiles = B / 16;                    // B = 262144 -> 16384

    hipLaunchKernelGGL(repack_kernel, dim3(16), dim3(256), 0, stream,
                       ew1, eb1, ew2, eb2, ew3, eb3, qp,
                       dw1, db1, dw2, db2, dw3, db3, ws);

    const int blocks = 1024;                      // 4096 waves -> 4 tiles/wave
    const int nwaves = blocks * (BLOCK / 64);
    hipLaunchKernelGGL(qnet_kernel, dim3(blocks), dim3(BLOCK), 0, stream,
                       state, ws, out, ntiles, nwaves);
}

// Round 15
// 25.256 us; speedup vs baseline: 2.5318x; 1.1355x over previous
//
#include <hip/hip_runtime.h>
#include <math.h>

#define SD 39
#define BLOCK 256

typedef _Float16 half8 __attribute__((ext_vector_type(8)));
typedef float f32x4 __attribute__((ext_vector_type(4)));

// ---- d_ws layout (dword offsets). All weight data pre-packed into per-lane
// MFMA fragments: frag arrays are [nfrag][64 lanes] of half8/f32x4 (16B each).
// Slot k-assignments are chosen by US and baked into BOTH the weight frags
// (repack) and the data frags (main kernel); MFMA pairs A-slot(g,j) with
// B-slot(g,j), so any consistent choice works.
#define DW_AW1 0      // 8 frags  (mt0..3 x ks0..1)   k = ks*32 + 8g + j ; 0 if k>=39
#define DW_AB1 2048   // 4 frags  f32x4 bias: eb1[mt*16+4g+r]
#define DW_AW2 3072   // 4 frags  (mt0..1 x ks0..1)   o1 = ks*32+16*(j>>2)+4g+(j&3)
#define DW_AB2 4096   // 2 frags  eb2[mt*16+4g+r]
#define DW_AW3 4608   // 1 frag   m=c<4: ew3[c][o2], o2=16*(j>>2)+4g+(j&3); else 0
#define DW_AB3 4864   // 1 frag   g==0 ? eb3[r] : 0
#define DW_AD1 5120   // 2 frags  (g==0&&j<4) ? dw1[(mt*16+c)*4+j] : 0
#define DW_AE1 5632   // 2 frags  db1[mt*16+4g+r]
#define DW_AD2 6144   // 1 frag   dw2[c*32 + 16*(j>>2)+4g+(j&3)]
#define DW_AE2 6400   // 1 frag   db2[4g+r]
#define DW_AD3 6656   // 1 frag   (c<8&&j<4) ? dw3[c*16+4g+j] : 0
#define DW_AE3 6912   // 1 frag   (4g+r<8) ? db3[4g+r] : 0
#define DW_QPE 7168   // qp[0,2,4,6]
#define DW_TOT 7172   // dwords (28688 B) -> staged to LDS per block

__global__ void repack_kernel(
    const float* __restrict__ ew1, const float* __restrict__ eb1,
    const float* __restrict__ ew2, const float* __restrict__ eb2,
    const float* __restrict__ ew3, const float* __restrict__ eb3,
    const float* __restrict__ qp,
    const float* __restrict__ dw1, const float* __restrict__ db1,
    const float* __restrict__ dw2, const float* __restrict__ db2,
    const float* __restrict__ dw3, const float* __restrict__ db3,
    float* __restrict__ ws)
{
    _Float16* wh = (_Float16*)ws;
    const int t0 = threadIdx.x + blockIdx.x * blockDim.x;
    const int stride = blockDim.x * gridDim.x;

    for (int i = t0; i < 8 * 512; i += stride) {          // AW1
        int frag = i >> 9, lane = (i >> 3) & 63, j = i & 7;
        int mt = frag >> 1, ks = frag & 1, g = lane >> 4, c = lane & 15;
        int m = mt * 16 + c, k = ks * 32 + 8 * g + j;
        wh[DW_AW1 * 2 + i] = (k < SD) ? (_Float16)ew1[m * SD + k] : (_Float16)0.0f;
    }
    for (int i = t0; i < 4 * 512; i += stride) {          // AW2
        int frag = i >> 9, lane = (i >> 3) & 63, j = i & 7;
        int mt = frag >> 1, ks = frag & 1, g = lane >> 4, c = lane & 15;
        int m = mt * 16 + c, o1 = ks * 32 + 16 * (j >> 2) + 4 * g + (j & 3);
        wh[DW_AW2 * 2 + i] = (_Float16)ew2[m * 64 + o1];
    }
    for (int i = t0; i < 512; i += stride) {              // AW3
        int lane = (i >> 3) & 63, j = i & 7, g = lane >> 4, c = lane & 15;
        int o2 = 16 * (j >> 2) + 4 * g + (j & 3);
        wh[DW_AW3 * 2 + i] = (c < 4) ? (_Float16)ew3[c * 32 + o2] : (_Float16)0.0f;
    }
    for (int i = t0; i < 2 * 512; i += stride) {          // AD1
        int frag = i >> 9, lane = (i >> 3) & 63, j = i & 7;
        int g = lane >> 4, c = lane & 15, m = frag * 16 + c;
        wh[DW_AD1 * 2 + i] = (g == 0 && j < 4) ? (_Float16)dw1[m * 4 + j] : (_Float16)0.0f;
    }
    for (int i = t0; i < 512; i += stride) {              // AD2
        int lane = (i >> 3) & 63, j = i & 7, g = lane >> 4, c = lane & 15;
        int k1 = 16 * (j >> 2) + 4 * g + (j & 3);
        wh[DW_AD2 * 2 + i] = (_Float16)dw2[c * 32 + k1];
    }
    for (int i = t0; i < 512; i += stride) {              // AD3
        int lane = (i >> 3) & 63, j = i & 7, g = lane >> 4, c = lane & 15;
        wh[DW_AD3 * 2 + i] = (c < 8 && j < 4) ? (_Float16)dw3[c * 16 + 4 * g + j]
                                              : (_Float16)0.0f;
    }
    for (int i = t0; i < 1024; i += stride) {             // AB1
        int mt = i >> 8, lane = (i >> 2) & 63, r = i & 3, g = lane >> 4;
        ws[DW_AB1 + i] = eb1[mt * 16 + 4 * g + r];
    }
    for (int i = t0; i < 512; i += stride) {              // AB2
        int mt = i >> 8, lane = (i >> 2) & 63, r = i & 3, g = lane >> 4;
        ws[DW_AB2 + i] = eb2[mt * 16 + 4 * g + r];
    }
    for (int i = t0; i < 256; i += stride) {              // AB3
        int lane = (i >> 2) & 63, r = i & 3, g = lane >> 4;
        ws[DW_AB3 + i] = (g == 0) ? eb3[r] : 0.0f;
    }
    for (int i = t0; i < 512; i += stride) {              // AE1
        int mt = i >> 8, lane = (i >> 2) & 63, r = i & 3, g = lane >> 4;
        ws[DW_AE1 + i] = db1[mt * 16 + 4 * g + r];
    }
    for (int i = t0; i < 256; i += stride) {              // AE2
        int lane = (i >> 2) & 63, r = i & 3, g = lane >> 4;
        ws[DW_AE2 + i] = db2[4 * g + r];
    }
    for (int i = t0; i < 256; i += stride) {              // AE3
        int lane = (i >> 2) & 63, r = i & 3, g = lane >> 4;
        ws[DW_AE3 + i] = (4 * g + r < 8) ? db3[4 * g + r] : 0.0f;
    }
    for (int i = t0; i < 4; i += stride) ws[DW_QPE + i] = qp[2 * i];
}

__global__ __launch_bounds__(BLOCK)
void qnet_kernel(const float* __restrict__ state,
                 const float* __restrict__ wsf,
                 float* __restrict__ out,
                 int ntiles, int nwaves)
{
    // Stage ALL weight fragments into LDS once per block: fragment re-reads
    // then ride the dedicated 128B/cyc LDS pipe (lane-linear ds_read_b128,
    // conflict-free), leaving the L1 pipe exclusively for the state stream.
    // (R14's per-tile global frag reloads put ~1.8MB/CU through the 64B/cyc
    // L1 return path ~= 12us -- the dominant cost.)
    __shared__ __align__(16) float lf[DW_TOT];
    {
        const float4* src4 = (const float4*)wsf;
        float4* dst4 = (float4*)lf;
        for (int i = threadIdx.x; i < DW_TOT / 4; i += BLOCK) dst4[i] = src4[i];
    }
    __syncthreads();

    const int lane = threadIdx.x & 63;
    const int g = lane >> 4, c = lane & 15;
    const int gwave = blockIdx.x * (BLOCK / 64) + (threadIdx.x >> 6);

    const half8* hws = (const half8*)lf;
    const f32x4* fws = (const f32x4*)lf;
    const float* qpep = lf + DW_QPE;          // wave-uniform -> broadcast read

    for (int tile = gwave; tile < ntiles; tile += nwaves) {
        const long long R = (long long)tile * 16;
        const float* sp = state + (R + c) * SD;

        // ---- state B-fragments. ks0 slots: col 8g+j (all live).
        //      ks1 slots: col 32+8g+j -> weights are ZERO for g>=1, so only
        //      g==0 lanes load cols 32..38 (exec-masked lanes issue no
        //      memory requests; others contribute exact 0 via weights). ----
        float4 s0 = *(const float4*)(sp + 8 * g);
        float4 s1 = *(const float4*)(sp + 8 * g + 4);
        float4 s2 = make_float4(0.f, 0.f, 0.f, 0.f);
        float4 s3 = make_float4(0.f, 0.f, 0.f, 0.f);
        if (g == 0) {
            s2 = *(const float4*)(sp + 32);   // cols 32..35
            s3 = *(const float4*)(sp + 35);   // cols 35..38 (in-bounds)
        }
        half8 x0, x1;
        x0[0] = (_Float16)s0.x; x0[1] = (_Float16)s0.y;
        x0[2] = (_Float16)s0.z; x0[3] = (_Float16)s0.w;
        x0[4] = (_Float16)s1.x; x0[5] = (_Float16)s1.y;
        x0[6] = (_Float16)s1.z; x0[7] = (_Float16)s1.w;
        x1[0] = (_Float16)s2.x; x1[1] = (_Float16)s2.y;
        x1[2] = (_Float16)s2.z; x1[3] = (_Float16)s2.w;
        x1[4] = (_Float16)s3.y; x1[5] = (_Float16)s3.z;
        x1[6] = (_Float16)s3.w; x1[7] = (_Float16)0.0f;

        // ---- L1: C1^T[o1][batch], 4 M-tiles x 2 K-steps ----
        f32x4 c1[4];
        #pragma unroll
        for (int mt = 0; mt < 4; mt++) {
            f32x4 acc = fws[DW_AB1 / 4 + mt * 64 + lane];
            acc = __builtin_amdgcn_mfma_f32_16x16x32_f16(
                      hws[DW_AW1 / 4 + (mt * 2 + 0) * 64 + lane], x0, acc, 0, 0, 0);
            acc = __builtin_amdgcn_mfma_f32_16x16x32_f16(
                      hws[DW_AW1 / 4 + (mt * 2 + 1) * 64 + lane], x1, acc, 0, 0, 0);
            c1[mt] = acc;
        }
        half8 hb0, hb1;
        #pragma unroll
        for (int j = 0; j < 8; j++) {
            hb0[j] = (_Float16)fmaxf(c1[j >> 2][j & 3], 0.0f);
            hb1[j] = (_Float16)fmaxf(c1[2 + (j >> 2)][j & 3], 0.0f);
        }

        // ---- L2: 2 M-tiles x 2 K-steps ----
        f32x4 c2[2];
        #pragma unroll
        for (int mt = 0; mt < 2; mt++) {
            f32x4 acc = fws[DW_AB2 / 4 + mt * 64 + lane];
            acc = __builtin_amdgcn_mfma_f32_16x16x32_f16(
                      hws[DW_AW2 / 4 + (mt * 2 + 0) * 64 + lane], hb0, acc, 0, 0, 0);
            acc = __builtin_amdgcn_mfma_f32_16x16x32_f16(
                      hws[DW_AW2 / 4 + (mt * 2 + 1) * 64 + lane], hb1, acc, 0, 0, 0);
            c2[mt] = acc;
        }
        half8 hb2;
        #pragma unroll
        for (int j = 0; j < 8; j++)
            hb2[j] = (_Float16)fmaxf(c2[j >> 2][j & 3], 0.0f);

        // ---- L3: enc^T (rows valid only in g==0 lanes; rest zeroed by wts) ----
        f32x4 e = __builtin_amdgcn_mfma_f32_16x16x32_f16(
                      hws[DW_AW3 / 4 + lane], hb2, fws[DW_AB3 / 4 + lane], 0, 0, 0);

        // ---- quantum: ev_i = prod_{j<=i} cos(tanh(e_j)*pi + qp[2j]) ----
        // (RZ cancels under Z-measure; CNOT chain -> bit i = b0^..^bi)
        float ev[4]; float cp = 1.0f;
        #pragma unroll
        for (int r = 0; r < 4; r++) {
            float ex = __expf(2.0f * e[r]);              // tanh = 1 - 2/(e^2x+1)
            float enc = 1.0f - 2.0f / (ex + 1.0f);
            float th = fmaf(enc, 3.14159265358979323846f, qpep[r]);
            cp *= __cosf(th);
            ev[r] = cp;
        }
        half8 evb;
        evb[0] = (_Float16)ev[0]; evb[1] = (_Float16)ev[1];
        evb[2] = (_Float16)ev[2]; evb[3] = (_Float16)ev[3];
        evb[4] = (_Float16)0.0f;  evb[5] = (_Float16)0.0f;
        evb[6] = (_Float16)0.0f;  evb[7] = (_Float16)0.0f;

        // ---- D1: 2 M-tiles, K=4(pad32) ----
        f32x4 d1c[2];
        #pragma unroll
        for (int mt = 0; mt < 2; mt++)
            d1c[mt] = __builtin_amdgcn_mfma_f32_16x16x32_f16(
                          hws[DW_AD1 / 4 + mt * 64 + lane], evb,
                          fws[DW_AE1 / 4 + mt * 64 + lane], 0, 0, 0);
        half8 db;
        #pragma unroll
        for (int j = 0; j < 8; j++)
            db[j] = (_Float16)fmaxf(d1c[j >> 2][j & 3], 0.0f);

        // ---- D2: K=32 ----
        f32x4 d2c = __builtin_amdgcn_mfma_f32_16x16x32_f16(
                        hws[DW_AD2 / 4 + lane], db, fws[DW_AE2 / 4 + lane], 0, 0, 0);
        half8 d2b;
        d2b[0] = (_Float16)fmaxf(d2c[0], 0.0f);
        d2b[1] = (_Float16)fmaxf(d2c[1], 0.0f);
        d2b[2] = (_Float16)fmaxf(d2c[2], 0.0f);
        d2b[3] = (_Float16)fmaxf(d2c[3], 0.0f);
        d2b[4] = (_Float16)0.0f; d2b[5] = (_Float16)0.0f;
        d2b[6] = (_Float16)0.0f; d2b[7] = (_Float16)0.0f;

        // ---- D3: K=16(pad32); out rows 0..7: g=0 -> dims 0-3, g=1 -> 4-7 ----
        f32x4 o = __builtin_amdgcn_mfma_f32_16x16x32_f16(
                      hws[DW_AD3 / 4 + lane], d2b, fws[DW_AE3 / 4 + lane], 0, 0, 0);

        if (lane < 32) {
            float4* op = (float4*)(out + (R + c) * 8 + 4 * g);
            *op = make_float4(o[0], o[1], o[2], o[3]);
        }
    }
}

extern "C" void kernel_launch(void* const* d_in, const int* in_sizes, int n_in,
                              void* d_out, int out_size, void* d_ws, size_t ws_size,
                              hipStream_t stream) {
    const float* state = (const float*)d_in[0];
    const float* ew1 = (const float*)d_in[1];
    const float* eb1 = (const float*)d_in[2];
    const float* ew2 = (const float*)d_in[3];
    const float* eb2 = (const float*)d_in[4];
    const float* ew3 = (const float*)d_in[5];
    const float* eb3 = (const float*)d_in[6];
    const float* qp  = (const float*)d_in[7];
    const float* dw1 = (const float*)d_in[8];
    const float* db1 = (const float*)d_in[9];
    const float* dw2 = (const float*)d_in[10];
    const float* db2 = (const float*)d_in[11];
    const float* dw3 = (const float*)d_in[12];
    const float* db3 = (const float*)d_in[13];
    float* out = (float*)d_out;
    float* ws  = (float*)d_ws;

    const int B = in_sizes[0] / SD;
    const int ntiles = B / 16;                    // 262144 -> 16384

    hipLaunchKernelGGL(repack_kernel, dim3(16), dim3(256), 0, stream,
                       ew1, eb1, ew2, eb2, ew3, eb3, qp,
                       dw1, db1, dw2, db2, dw3, db3, ws);

    const int blocks = 1024;                      // 4096 waves -> 4 tiles/wave
    const int nwaves = blocks * (BLOCK / 64);
    hipLaunchKernelGGL(qnet_kernel, dim3(blocks), dim3(BLOCK), 0, stream,
                       state, ws, out, ntiles, nwaves);
}